// Round 4
// baseline (1090.699 us; speedup 1.0000x reference)
//
#include <hip/hip_runtime.h>
#include <math.h>

#define KNN 16
#define NPTS 8192
#define PTCH 256
#define NPATCH 32
#define NBATCH 4
#define NQ 64
#define CAPP 50          // survivor slots per lane-segment (stride 100 B: conflict-free-ish)
#define LAMBDA_T 64.0    // target E[survivors] per query (P(<16) ~ 2e-12, Binomial-exact)

__global__ void zero2_kernel(float* out) { out[0] = 0.0f; out[1] = 0.0f; }

// ---------- analytic gate: E[#points within distance s of a query at radius r],
// for N iid N(0,I3) points. Closed form via spherical-cap shell integral.
__device__ double lam_ball(double r, double s)
{
    const double C     = 0.063493635934241;      // (2*pi)^{-3/2}
    const double SQ2PI = 2.5066282746310002;     // sqrt(2*pi)
    const double IS2   = 0.7071067811865476;     // 1/sqrt(2)
    double a = fabs(r - s), b = r + s;
    double I = 2.0 * (exp(-0.5 * b * b) - exp(-0.5 * a * a))
             + r * SQ2PI * (erf(b * IS2) - erf(a * IS2));
    double M = C * (M_PI / r) * I;
    if (s > r) {   // ball contains origin: add full-shell mass for t in [0, s-r]
        double u = s - r;
        M += 4.0 * M_PI * C * (sqrt(0.5 * M_PI) * erf(u * IS2) - u * exp(-0.5 * u * u));
    }
    return (double)NPTS * M;
}

__global__ void gate_kernel(const float* __restrict__ pts, float* __restrict__ gates)
{
    int i = blockIdx.x * 256 + threadIdx.x;        // 0 .. B*N-1
    double qx = pts[i * 3 + 0], qy = pts[i * 3 + 1], qz = pts[i * 3 + 2];
    double r = sqrt(qx * qx + qy * qy + qz * qz);
    if (r < 1e-6) r = 1e-6;
    double lo = 0.0, hi = 12.0;                    // lam(12) = N >> target; monotone
    for (int it = 0; it < 46; ++it) {
        double mid = 0.5 * (lo + hi);
        if (lam_ball(r, mid) < LAMBDA_T) lo = mid; else hi = mid;
    }
    gates[i] = (float)(hi * hi);                   // gate on squared distance
}

// ---------- 3x3 symmetric eigensolver (fp64 cyclic Jacobi), as verified in R1-R3
__device__ __forceinline__ void jrot(double& app, double& aqq, double& apq,
                                     double& arp, double& arq,
                                     double& vp0, double& vq0,
                                     double& vp1, double& vq1,
                                     double& vp2, double& vq2)
{
    double g = apq;
    if (g == 0.0) return;
    double theta = (aqq - app) / (2.0 * g);
    double at = fabs(theta);
    double t = (at > 1.0e154) ? (0.5 / theta)
                              : (copysign(1.0, theta) / (at + sqrt(theta * theta + 1.0)));
    double c = 1.0 / sqrt(t * t + 1.0);
    double s = t * c;
    double tau = s / (1.0 + c);
    app -= t * g;
    aqq += t * g;
    apq = 0.0;
    double rp = arp, rq = arq;
    arp = rp - s * (rq + tau * rp);
    arq = rq + s * (rp - tau * rq);
    double p0 = vp0, q0 = vq0;
    vp0 = p0 - s * (q0 + tau * p0); vq0 = q0 + s * (p0 - tau * q0);
    double p1 = vp1, q1 = vq1;
    vp1 = p1 - s * (q1 + tau * p1); vq1 = q1 + s * (p1 - tau * q1);
    double p2 = vp2, q2 = vq2;
    vp2 = p2 - s * (q2 + tau * p2); vq2 = q2 + s * (p2 - tau * q2);
}

__device__ __forceinline__ void eig3(double a00, double a11, double a22,
                                     double a01, double a02, double a12,
                                     double& nx, double& ny, double& nz,
                                     double& lmin, double& lsum)
{
    double v00 = 1, v01 = 0, v02 = 0;
    double v10 = 0, v11 = 1, v12 = 0;
    double v20 = 0, v21 = 0, v22 = 1;
    double scale = fabs(a00) + fabs(a11) + fabs(a22) + fabs(a01) + fabs(a02) + fabs(a12);
    if (scale > 0.0) {
        for (int sweep = 0; sweep < 6; ++sweep) {
            double off = fabs(a01) + fabs(a02) + fabs(a12);
            if (off <= scale * 1e-15) break;
            jrot(a00, a11, a01, a02, a12, v00, v01, v10, v11, v20, v21);
            jrot(a00, a22, a02, a01, a12, v00, v02, v10, v12, v20, v22);
            jrot(a11, a22, a12, a01, a02, v01, v02, v11, v12, v21, v22);
        }
    }
    lsum = a00 + a11 + a22;
    lmin = a00; nx = v00; ny = v10; nz = v20;
    if (a11 < lmin) { lmin = a11; nx = v01; ny = v11; nz = v21; }
    if (a22 < lmin) { lmin = a22; nx = v02; ny = v12; nz = v22; }
}

// u32 key: (d2 float bits, low 13 mantissa bits cleared) | idx(13b). Ties -> lower idx.
__device__ __forceinline__ unsigned mkkey(float d2, unsigned idx) {
    return (__float_as_uint(d2) & 0xFFFFE000u) | idx;
}

// Caller guarantees key < L[15]. Sorted-ascending bubble (v_min/v_max pairs).
__device__ __forceinline__ void insert16(unsigned key, unsigned* L)
{
    L[KNN - 1] = key;
    #pragma unroll
    for (int m = KNN - 1; m >= 1; --m) {
        unsigned a = L[m - 1], b = L[m];
        L[m - 1] = min(a, b);
        L[m]     = max(a, b);
    }
}

// Block = 256 threads, 64 queries (quarter patch). Wave w scans tiles [w*8,w*8+8)
// with branchless gate-filter appends into a per-lane LDS survivor segment.
// Phase 2: wave0 = exact top-16 from survivors (+validity, + exact fallback) + eig;
// waves1/2 = patch kNN halves + eig; wave3 idle in phase 2.
__global__ void __launch_bounds__(256)
spl_main(const float* __restrict__ pts, const float* __restrict__ gates,
         float* __restrict__ out)
{
    __shared__ float4 tileW[4][PTCH];              // 16 KB per-wave candidate tiles
    __shared__ float4 pbuf4[PTCH];                 // 4 KB own patch
    __shared__ unsigned short surv[4 * NQ * CAPP]; // 25.6 KB survivor indices
    __shared__ unsigned cnts[4 * NQ];              // 1 KB survivor counts
    __shared__ unsigned pListBuf[NQ * KNN];        // 4 KB wave2 patch half-list
    __shared__ double xbuf[NQ * 4];                // 2 KB patch normal+sv
    // total 52 KB -> 3 blocks/CU

    const int t = threadIdx.x;
    const int w = t >> 6;
    const int q = t & 63;
    const int p = blockIdx.x;
    const int quarter = blockIdx.y;
    const int b = blockIdx.z;

    const float* base = pts + (size_t)b * (NPTS * 3);
    const int qi = p * PTCH + quarter * NQ + q;

    const float qx = base[qi * 3 + 0];
    const float qy = base[qi * 3 + 1];
    const float qz = base[qi * 3 + 2];
    const float g = gates ? gates[b * NPTS + qi] : 3.0e38f;  // inf -> fallback path (exact)

    // Stage own patch into padded LDS (read by waves1/2 after B1).
    {
        const float* src = base + p * (PTCH * 3);
        float* dst = (float*)pbuf4;
        #pragma unroll
        for (int s = 0; s < 3; ++s) {
            int f = t + s * 256;
            int j = f / 3;
            int c = f - 3 * j;
            dst[j * 4 + c] = src[f];
        }
    }

    float4* myTile = tileW[w];
    const int lbase = t * CAPP;
    unsigned cnt = 0;

    // Prefetch tile 0 of this wave's substream: lane q holds points {q,64+q,128+q,192+q}.
    float px[4], py[4], pz[4];
    {
        const float* src = base + (w * 8) * (PTCH * 3);
        #pragma unroll
        for (int k = 0; k < 4; ++k) {
            int i3 = (k * 64 + q) * 3;
            px[k] = src[i3]; py[k] = src[i3 + 1]; pz[k] = src[i3 + 2];
        }
    }

    #pragma unroll 1
    for (int tl = 0; tl < 8; ++tl) {
        // Lane-contiguous b128 writes (16 B lane stride -> conflict-free).
        #pragma unroll
        for (int k = 0; k < 4; ++k)
            myTile[k * 64 + q] = make_float4(px[k], py[k], pz[k], 0.f);
        if (tl < 7) {
            const float* src = base + (w * 8 + tl + 1) * (PTCH * 3);
            #pragma unroll
            for (int k = 0; k < 4; ++k) {
                int i3 = (k * 64 + q) * 3;
                px[k] = src[i3]; py[k] = src[i3 + 1]; pz[k] = src[i3 + 2];
            }
        }
        const unsigned gb = (unsigned)((w * 8 + tl) * PTCH);
        #pragma unroll 1
        for (int j = 0; j < PTCH; j += 8) {
            #pragma unroll
            for (int u = 0; u < 8; ++u) {
                float4 c = myTile[j + u];          // ds_read_b128 broadcast
                float dx = qx - c.x, dy = qy - c.y, dz = qz - c.z;
                float d2 = dx * dx + dy * dy + dz * dz;
                // branchless filter-append: write always, advance cnt on pass
                surv[lbase + min(cnt, (unsigned)(CAPP - 1))] = (unsigned short)(gb + j + u);
                cnt += (d2 < g) ? 1u : 0u;
            }
        }
    }
    cnts[t] = cnt;
    __syncthreads();   // B1: survivors + counts + pbuf ready

    double ngx = 0, ngy = 0, ngz = 0, svg = 0;
    unsigned pl[KNN];

    if (w == 0) {
        unsigned gl[KNN];
        #pragma unroll
        for (int m = 0; m < KNN; ++m) gl[m] = 0xFFFFFFFFu;
        const unsigned c0 = cnts[q], c1 = cnts[64 + q], c2 = cnts[128 + q], c3 = cnts[192 + q];
        bool invalid = (c0 > CAPP) | (c1 > CAPP) | (c2 > CAPP) | (c3 > CAPP) |
                       ((c0 + c1 + c2 + c3) < KNN);
        if (!invalid) {
            #pragma unroll 1
            for (int s = 0; s < 4; ++s) {
                const unsigned cs = cnts[s * 64 + q];
                const unsigned short* sv = &surv[(s * 64 + q) * CAPP];
                #pragma unroll 1
                for (unsigned m = 0; m < cs; ++m) {
                    unsigned idx = sv[m];
                    float cx = base[idx * 3 + 0];
                    float cy = base[idx * 3 + 1];
                    float cz = base[idx * 3 + 2];
                    float dx = qx - cx, dy = qy - cy, dz = qz - cz;
                    float d2 = dx * dx + dy * dy + dz * dz;
                    unsigned k = mkkey(d2, idx);
                    if (k < gl[KNN - 1]) insert16(k, gl);
                }
            }
            // key-quantization bucket check: every non-survivor has d2 >= g >
            // upper-bound of the 16th key's bucket => its key strictly larger. Airtight.
            float upper = __uint_as_float((gl[KNN - 1] & 0xFFFFE000u) + 0x2000u);
            invalid = !(upper <= g);
        }
        if (__any(invalid ? 1 : 0)) {
            if (invalid) {   // exact fallback: full gated-bubble scan (prob ~1e-12/query)
                #pragma unroll
                for (int m = 0; m < KNN; ++m) gl[m] = 0xFFFFFFFFu;
                #pragma unroll 1
                for (int i = 0; i < NPTS; ++i) {
                    float cx = base[i * 3 + 0];
                    float cy = base[i * 3 + 1];
                    float cz = base[i * 3 + 2];
                    float dx = qx - cx, dy = qy - cy, dz = qz - cz;
                    float d2 = dx * dx + dy * dy + dz * dz;
                    unsigned k = mkkey(d2, (unsigned)i);
                    if (k < gl[KNN - 1]) insert16(k, gl);
                }
            }
        }
        // Global covariance in fp64 + eigensolve.
        double c00 = 0, c11 = 0, c22 = 0, c01 = 0, c02 = 0, c12 = 0;
        const double qxd = qx, qyd = qy, qzd = qz;
        #pragma unroll
        for (int m = 0; m < KNN; ++m) {
            int idx = (int)(gl[m] & 0x1FFFu);
            double dx = (double)base[idx * 3 + 0] - qxd;
            double dy = (double)base[idx * 3 + 1] - qyd;
            double dz = (double)base[idx * 3 + 2] - qzd;
            c00 += dx * dx; c11 += dy * dy; c22 += dz * dz;
            c01 += dx * dy; c02 += dx * dz; c12 += dy * dz;
        }
        double lmin, lsum;
        eig3(c00, c11, c22, c01, c02, c12, ngx, ngy, ngz, lmin, lsum);
        svg = lmin / lsum;
    } else if (w <= 2) {
        // Patch kNN half-scan (local indices), gated bubble (only 128 candidates).
        #pragma unroll
        for (int m = 0; m < KNN; ++m) pl[m] = 0xFFFFFFFFu;
        const int c0r = (w == 1) ? 0 : 128;
        #pragma unroll 1
        for (int j = c0r; j < c0r + 128; ++j) {
            float4 c = pbuf4[j];
            float dx = qx - c.x, dy = qy - c.y, dz = qz - c.z;
            float d2 = dx * dx + dy * dy + dz * dz;
            unsigned k = mkkey(d2, (unsigned)j);
            if (k < pl[KNN - 1]) insert16(k, pl);
        }
        if (w == 2) {
            #pragma unroll
            for (int m = 0; m < KNN; ++m) pListBuf[q * KNN + m] = pl[m];
        }
    }
    __syncthreads();   // B2: wave2's half-list ready

    if (w == 1) {
        for (int m = 0; m < KNN; ++m) {
            unsigned key = pListBuf[q * KNN + m];
            if (key >= pl[KNN - 1]) break;
            insert16(key, pl);
        }
        double c00 = 0, c11 = 0, c22 = 0, c01 = 0, c02 = 0, c12 = 0;
        const double qxd = qx, qyd = qy, qzd = qz;
        #pragma unroll
        for (int m = 0; m < KNN; ++m) {
            int idx = (int)(pl[m] & 0x1FFFu);
            float4 cpt = pbuf4[idx];
            double dx = (double)cpt.x - qxd;
            double dy = (double)cpt.y - qyd;
            double dz = (double)cpt.z - qzd;
            c00 += dx * dx; c11 += dy * dy; c22 += dz * dz;
            c01 += dx * dy; c02 += dx * dz; c12 += dy * dz;
        }
        double nx, ny, nz, lmin, lsum;
        eig3(c00, c11, c22, c01, c02, c12, nx, ny, nz, lmin, lsum);
        xbuf[q * 4 + 0] = nx;
        xbuf[q * 4 + 1] = ny;
        xbuf[q * 4 + 2] = nz;
        xbuf[q * 4 + 3] = lmin / lsum;
    }
    __syncthreads();   // B3: patch results ready

    if (w == 0) {
        double npx = xbuf[q * 4 + 0];
        double npy = xbuf[q * 4 + 1];
        double npz = xbuf[q * 4 + 2];
        double svp = xbuf[q * 4 + 3];
        double dx = fabs(npx) - fabs(ngx);
        double dy = fabs(npy) - fabs(ngy);
        double dz = fabs(npz) - fabs(ngz);
        double ln  = sqrt(dx * dx + dy * dy + dz * dz);
        double ds  = svp - svg;
        double lsv = ds * ds;
        #pragma unroll
        for (int o = 32; o > 0; o >>= 1) {
            ln  += __shfl_down(ln, o);
            lsv += __shfl_down(lsv, o);
        }
        if (q == 0) {
            const double inv = 1.0 / (double)(NBATCH * NPTS);
            atomicAdd(&out[0], (float)(ln * inv));
            atomicAdd(&out[1], (float)(lsv * inv));
        }
    }
}

extern "C" void kernel_launch(void* const* d_in, const int* in_sizes, int n_in,
                              void* d_out, int out_size, void* d_ws, size_t ws_size,
                              hipStream_t stream)
{
    const float* pts = (const float*)d_in[0];
    float* out = (float*)d_out;
    const size_t gate_bytes = (size_t)(NBATCH * NPTS) * sizeof(float);
    float* gates = (ws_size >= gate_bytes) ? (float*)d_ws : nullptr;

    hipLaunchKernelGGL(zero2_kernel, dim3(1), dim3(1), 0, stream, out);
    if (gates)
        hipLaunchKernelGGL(gate_kernel, dim3(NBATCH * NPTS / 256), dim3(256), 0, stream,
                           pts, gates);
    dim3 grid(NPATCH, 4, NBATCH);
    hipLaunchKernelGGL(spl_main, grid, dim3(256), 0, stream, pts, gates, out);
}

// Round 5
// 1050.471 us; speedup vs baseline: 1.0383x; 1.0383x over previous
//
#include <hip/hip_runtime.h>
#include <math.h>

#define KNN 16
#define NPTS 8192
#define PTCH 256
#define NPATCH 32
#define NBATCH 4
#define NQ 64            // queries per block (quarter patch)
#define TILE 1024        // candidates per LDS tile
#define SSTRIDE 130      // survivor slots/query: 130 u16 = 65 words -> bank stride 1
#define LAMBDA_T 64.0    // target E[survivors]/query; P(<16) ~ 2e-12

__global__ void zero2_kernel(float* out) { out[0] = 0.0f; out[1] = 0.0f; }

// E[#points within distance s of a query at radius r], N iid N(0,I3).
__device__ double lam_ball(double r, double s)
{
    const double C     = 0.063493635934241;      // (2*pi)^{-3/2}
    const double SQ2PI = 2.5066282746310002;
    const double IS2   = 0.7071067811865476;
    double a = fabs(r - s), b = r + s;
    double I = 2.0 * (exp(-0.5 * b * b) - exp(-0.5 * a * a))
             + r * SQ2PI * (erf(b * IS2) - erf(a * IS2));
    double M = C * (M_PI / r) * I;
    if (s > r) {
        double u = s - r;
        M += 4.0 * M_PI * C * (sqrt(0.5 * M_PI) * erf(u * IS2) - u * exp(-0.5 * u * u));
    }
    return (double)NPTS * M;
}

__global__ void gate_kernel(const float* __restrict__ pts, float* __restrict__ gates)
{
    int i = blockIdx.x * 256 + threadIdx.x;
    double qx = pts[i * 3 + 0], qy = pts[i * 3 + 1], qz = pts[i * 3 + 2];
    double r = sqrt(qx * qx + qy * qy + qz * qz);
    if (r < 1e-6) r = 1e-6;
    double lo = 0.0, hi = 12.0;
    for (int it = 0; it < 24; ++it) {   // 24 iters: gate precision ~1e-6; margin check covers rest
        double mid = 0.5 * (lo + hi);
        if (lam_ball(r, mid) < LAMBDA_T) lo = mid; else hi = mid;
    }
    gates[i] = (float)(hi * hi);
}

// ---------- fp64 cyclic Jacobi 3x3 (verified R1-R4) ----------
__device__ __forceinline__ void jrot(double& app, double& aqq, double& apq,
                                     double& arp, double& arq,
                                     double& vp0, double& vq0,
                                     double& vp1, double& vq1,
                                     double& vp2, double& vq2)
{
    double g = apq;
    if (g == 0.0) return;
    double theta = (aqq - app) / (2.0 * g);
    double at = fabs(theta);
    double t = (at > 1.0e154) ? (0.5 / theta)
                              : (copysign(1.0, theta) / (at + sqrt(theta * theta + 1.0)));
    double c = 1.0 / sqrt(t * t + 1.0);
    double s = t * c;
    double tau = s / (1.0 + c);
    app -= t * g;
    aqq += t * g;
    apq = 0.0;
    double rp = arp, rq = arq;
    arp = rp - s * (rq + tau * rp);
    arq = rq + s * (rp - tau * rq);
    double p0 = vp0, q0 = vq0;
    vp0 = p0 - s * (q0 + tau * p0); vq0 = q0 + s * (p0 - tau * q0);
    double p1 = vp1, q1 = vq1;
    vp1 = p1 - s * (q1 + tau * p1); vq1 = q1 + s * (p1 - tau * q1);
    double p2 = vp2, q2 = vq2;
    vp2 = p2 - s * (q2 + tau * p2); vq2 = q2 + s * (p2 - tau * q2);
}

__device__ __forceinline__ void eig3(double a00, double a11, double a22,
                                     double a01, double a02, double a12,
                                     double& nx, double& ny, double& nz,
                                     double& lmin, double& lsum)
{
    double v00 = 1, v01 = 0, v02 = 0;
    double v10 = 0, v11 = 1, v12 = 0;
    double v20 = 0, v21 = 0, v22 = 1;
    double scale = fabs(a00) + fabs(a11) + fabs(a22) + fabs(a01) + fabs(a02) + fabs(a12);
    if (scale > 0.0) {
        for (int sweep = 0; sweep < 6; ++sweep) {
            double off = fabs(a01) + fabs(a02) + fabs(a12);
            if (off <= scale * 1e-15) break;
            jrot(a00, a11, a01, a02, a12, v00, v01, v10, v11, v20, v21);
            jrot(a00, a22, a02, a01, a12, v00, v02, v10, v12, v20, v22);
            jrot(a11, a22, a12, a01, a02, v01, v02, v11, v12, v21, v22);
        }
    }
    lsum = a00 + a11 + a22;
    lmin = a00; nx = v00; ny = v10; nz = v20;
    if (a11 < lmin) { lmin = a11; nx = v01; ny = v11; nz = v21; }
    if (a22 < lmin) { lmin = a22; nx = v02; ny = v12; nz = v22; }
}

// u32 key: (d2 float bits, low 13 mantissa bits cleared) | idx(13b). Ties -> lower idx.
__device__ __forceinline__ unsigned mkkey(float d2, unsigned idx) {
    return (__float_as_uint(d2) & 0xFFFFE000u) | idx;
}

// Caller guarantees key < L[15]. Sorted-ascending bubble (v_min/v_max pairs).
__device__ __forceinline__ void insert16(unsigned key, unsigned* L)
{
    L[KNN - 1] = key;
    #pragma unroll
    for (int m = KNN - 1; m >= 1; --m) {
        unsigned a = L[m - 1], b = L[m];
        L[m - 1] = min(a, b);
        L[m]     = max(a, b);
    }
}

__device__ __forceinline__ float rfl(float x) {
    return __int_as_float(__builtin_amdgcn_readfirstlane(__float_as_int(x)));
}
__device__ __forceinline__ unsigned mbcnt64(unsigned long long m) {
    return __builtin_amdgcn_mbcnt_hi((unsigned)(m >> 32),
           __builtin_amdgcn_mbcnt_lo((unsigned)m, 0u));
}

// Block = 256 threads, 64 queries. Phase A: each wave filters ALL 8192 candidates
// (lane = candidate) against its 16 queries (SGPR-resident), ballot-compacting
// survivor indices into LDS. Phase B: wave0 = exact top-16 from survivors
// (+margin check + exact fallback) + fp64 cov/eig; waves1/2 = patch kNN + eig.
__global__ void __launch_bounds__(256)
spl_main(const float* __restrict__ pts, const float* __restrict__ gates,
         float* __restrict__ out)
{
    __shared__ float4 tile4[TILE];                 // 16 KB candidate tile (x,y,z,0.5|c|^2)
    __shared__ float4 pbuf4[PTCH];                 // 4 KB own patch
    __shared__ unsigned short surv[NQ * SSTRIDE];  // 16.25 KB survivor indices
    __shared__ unsigned cnts[NQ];                  // 256 B survivor counts
    __shared__ unsigned pListBuf[NQ * KNN];        // 4 KB wave2 patch half-list
    __shared__ double xbuf[NQ * 4];                // 2 KB patch normal+sv
    // ~43 KB -> 3 blocks/CU capacity

    const int t = threadIdx.x;
    const int w = t >> 6;
    const int lane = t & 63;
    const int p = blockIdx.x;
    const int quarter = blockIdx.y;
    const int b = blockIdx.z;

    const float* base = pts + (size_t)b * (NPTS * 3);
    const int qbase = p * PTCH + quarter * NQ;

    // Stage own patch into padded LDS (read by waves1/2 after B1).
    {
        const float* src = base + p * (PTCH * 3);
        float* dst = (float*)pbuf4;
        #pragma unroll
        for (int s = 0; s < 3; ++s) {
            int f = t + s * 256;
            int j = f / 3;
            int c = f - 3 * j;
            dst[j * 4 + c] = src[f];
        }
    }

    // This wave's 16 filter-queries: wave-uniform coords + thresholds in SGPRs.
    float sqx[16], sqy[16], sqz[16], shq[16];
    unsigned scnt[16];
    #pragma unroll
    for (int u = 0; u < 16; ++u) {
        int qi = qbase + w * 16 + u;
        float x = base[qi * 3 + 0], y = base[qi * 3 + 1], z = base[qi * 3 + 2];
        float gg = gates ? gates[b * NPTS + qi] : 3.0e38f;
        sqx[u] = rfl(x); sqy[u] = rfl(y); sqz[u] = rfl(z);
        shq[u] = rfl(0.5f * (gg - (x * x + y * y + z * z)));
        scnt[u] = 0;
    }

    // ---- Phase A: ballot-compacted gate filter ----
    #pragma unroll 1
    for (int t8 = 0; t8 < NPTS / TILE; ++t8) {
        __syncthreads();
        const int tb = t8 * TILE;
        #pragma unroll
        for (int k = 0; k < 4; ++k) {
            int ci = tb + k * 256 + t;
            float x = base[ci * 3 + 0], y = base[ci * 3 + 1], z = base[ci * 3 + 2];
            tile4[k * 256 + t] = make_float4(x, y, z, 0.5f * (x * x + y * y + z * z));
        }
        __syncthreads();
        #pragma unroll 1
        for (int it = 0; it < TILE / 64; ++it) {
            float4 c = tile4[it * 64 + lane];          // contiguous b128, conflict-free
            unsigned gidx = (unsigned)(tb + it * 64 + lane);
            #pragma unroll
            for (int u = 0; u < 16; ++u) {
                // d2 < g  <=>  0.5|c|^2 - q.c < 0.5(g - |q|^2)
                float tt = fmaf(-c.x, sqx[u], c.w);
                tt = fmaf(-c.y, sqy[u], tt);
                tt = fmaf(-c.z, sqz[u], tt);
                bool pass = tt < shq[u];
                unsigned long long m = __ballot(pass);
                if (m) {
                    unsigned pre = mbcnt64(m);         // set bits below my lane
                    if (pass) {
                        unsigned slot = scnt[u] + pre;
                        slot = slot < (SSTRIDE - 1) ? slot : (SSTRIDE - 1);
                        surv[(w * 16 + u) * SSTRIDE + slot] = (unsigned short)gidx;
                    }
                    scnt[u] += (unsigned)__popcll(m);  // wave-uniform (SGPR)
                }
            }
        }
    }
    if (lane == 0) {
        #pragma unroll
        for (int u = 0; u < 16; ++u) cnts[w * 16 + u] = scnt[u];
    }
    __syncthreads();   // B1

    // ---- Phase B ----
    double ngx = 0, ngy = 0, ngz = 0, svg = 0;
    unsigned pl[KNN];
    float pqx = 0.f, pqy = 0.f, pqz = 0.f;
    if (w <= 2) {
        int qi = qbase + lane;
        pqx = base[qi * 3 + 0];
        pqy = base[qi * 3 + 1];
        pqz = base[qi * 3 + 2];
    }

    if (w == 0) {
        const float g = gates ? gates[b * NPTS + qbase + lane] : 3.0e38f;
        unsigned gl[KNN];
        #pragma unroll
        for (int m = 0; m < KNN; ++m) gl[m] = 0xFFFFFFFFu;
        unsigned myCnt = cnts[lane];
        bool invalid = (myCnt < KNN) || (myCnt > SSTRIDE);
        if (!invalid) {
            #pragma unroll 1
            for (unsigned m = 0; m < myCnt; ++m) {
                unsigned idx = surv[lane * SSTRIDE + m];
                float cx = base[idx * 3 + 0];
                float cy = base[idx * 3 + 1];
                float cz = base[idx * 3 + 2];
                float dx = pqx - cx, dy = pqy - cy, dz = pqz - cz;
                float d2 = dx * dx + dy * dy + dz * dz;   // reference-form d2
                unsigned k = mkkey(d2, idx);
                if (k < gl[KNN - 1]) insert16(k, gl);
            }
            // margin check: every filtered-out point provably outside 16th bucket
            float upper = __uint_as_float((gl[KNN - 1] & 0xFFFFE000u) + 0x2000u);
            invalid = !(upper < g * 0.999f - 1e-5f);
        }
        if (__any(invalid ? 1 : 0)) {
            if (invalid) {   // exact fallback (P ~ 1e-12/query)
                #pragma unroll
                for (int m = 0; m < KNN; ++m) gl[m] = 0xFFFFFFFFu;
                #pragma unroll 1
                for (int i = 0; i < NPTS; ++i) {
                    float cx = base[i * 3 + 0];
                    float cy = base[i * 3 + 1];
                    float cz = base[i * 3 + 2];
                    float dx = pqx - cx, dy = pqy - cy, dz = pqz - cz;
                    float d2 = dx * dx + dy * dy + dz * dz;
                    unsigned k = mkkey(d2, (unsigned)i);
                    if (k < gl[KNN - 1]) insert16(k, gl);
                }
            }
        }
        double c00 = 0, c11 = 0, c22 = 0, c01 = 0, c02 = 0, c12 = 0;
        const double qxd = pqx, qyd = pqy, qzd = pqz;
        #pragma unroll
        for (int m = 0; m < KNN; ++m) {
            int idx = (int)(gl[m] & 0x1FFFu);
            double dx = (double)base[idx * 3 + 0] - qxd;
            double dy = (double)base[idx * 3 + 1] - qyd;
            double dz = (double)base[idx * 3 + 2] - qzd;
            c00 += dx * dx; c11 += dy * dy; c22 += dz * dz;
            c01 += dx * dy; c02 += dx * dz; c12 += dy * dz;
        }
        double lmin, lsum;
        eig3(c00, c11, c22, c01, c02, c12, ngx, ngy, ngz, lmin, lsum);
        svg = lmin / lsum;
    } else if (w <= 2) {
        // Patch kNN half-scan (local indices), gated bubble over 128 candidates.
        #pragma unroll
        for (int m = 0; m < KNN; ++m) pl[m] = 0xFFFFFFFFu;
        const int c0r = (w == 1) ? 0 : 128;
        #pragma unroll 1
        for (int j = c0r; j < c0r + 128; ++j) {
            float4 c = pbuf4[j];
            float dx = pqx - c.x, dy = pqy - c.y, dz = pqz - c.z;
            float d2 = dx * dx + dy * dy + dz * dz;
            unsigned k = mkkey(d2, (unsigned)j);
            if (k < pl[KNN - 1]) insert16(k, pl);
        }
        if (w == 2) {
            #pragma unroll
            for (int m = 0; m < KNN; ++m) pListBuf[lane * KNN + m] = pl[m];
        }
    }
    __syncthreads();   // B2

    if (w == 1) {
        for (int m = 0; m < KNN; ++m) {
            unsigned key = pListBuf[lane * KNN + m];
            if (key >= pl[KNN - 1]) break;
            insert16(key, pl);
        }
        double c00 = 0, c11 = 0, c22 = 0, c01 = 0, c02 = 0, c12 = 0;
        const double qxd = pqx, qyd = pqy, qzd = pqz;
        #pragma unroll
        for (int m = 0; m < KNN; ++m) {
            int idx = (int)(pl[m] & 0x1FFFu);
            float4 cpt = pbuf4[idx];
            double dx = (double)cpt.x - qxd;
            double dy = (double)cpt.y - qyd;
            double dz = (double)cpt.z - qzd;
            c00 += dx * dx; c11 += dy * dy; c22 += dz * dz;
            c01 += dx * dy; c02 += dx * dz; c12 += dy * dz;
        }
        double nx, ny, nz, lmin, lsum;
        eig3(c00, c11, c22, c01, c02, c12, nx, ny, nz, lmin, lsum);
        xbuf[lane * 4 + 0] = nx;
        xbuf[lane * 4 + 1] = ny;
        xbuf[lane * 4 + 2] = nz;
        xbuf[lane * 4 + 3] = lmin / lsum;
    }
    __syncthreads();   // B3

    if (w == 0) {
        double npx = xbuf[lane * 4 + 0];
        double npy = xbuf[lane * 4 + 1];
        double npz = xbuf[lane * 4 + 2];
        double svp = xbuf[lane * 4 + 3];
        double dx = fabs(npx) - fabs(ngx);
        double dy = fabs(npy) - fabs(ngy);
        double dz = fabs(npz) - fabs(ngz);
        double ln  = sqrt(dx * dx + dy * dy + dz * dz);
        double ds  = svp - svg;
        double lsv = ds * ds;
        #pragma unroll
        for (int o = 32; o > 0; o >>= 1) {
            ln  += __shfl_down(ln, o);
            lsv += __shfl_down(lsv, o);
        }
        if (lane == 0) {
            const double inv = 1.0 / (double)(NBATCH * NPTS);
            atomicAdd(&out[0], (float)(ln * inv));
            atomicAdd(&out[1], (float)(lsv * inv));
        }
    }
}

extern "C" void kernel_launch(void* const* d_in, const int* in_sizes, int n_in,
                              void* d_out, int out_size, void* d_ws, size_t ws_size,
                              hipStream_t stream)
{
    const float* pts = (const float*)d_in[0];
    float* out = (float*)d_out;
    const size_t gate_bytes = (size_t)(NBATCH * NPTS) * sizeof(float);
    float* gates = (ws_size >= gate_bytes) ? (float*)d_ws : nullptr;

    hipLaunchKernelGGL(zero2_kernel, dim3(1), dim3(1), 0, stream, out);
    if (gates)
        hipLaunchKernelGGL(gate_kernel, dim3(NBATCH * NPTS / 256), dim3(256), 0, stream,
                           pts, gates);
    dim3 grid(NPATCH, 4, NBATCH);
    hipLaunchKernelGGL(spl_main, grid, dim3(256), 0, stream, pts, gates, out);
}

// Round 6
// 212.420 us; speedup vs baseline: 5.1346x; 4.9453x over previous
//
#include <hip/hip_runtime.h>
#include <math.h>

#define KNN 16
#define NPTS 8192
#define PTCH 256
#define NPATCH 32
#define NBATCH 4
#define NQ 64            // queries per block (quarter patch)
#define TILE 1024        // candidates per LDS tile
#define SSTRIDE 130      // survivor slots/query (mean 64, +8sigma)
#define LAMBDA_T 64.0    // target E[survivors]/query

// E[#points within distance s of a query at radius r], N iid N(0,I3).
// Cap-shell integral: primitive e^{-t^2/2}[(t-r)^2+2-s^2] + 2r*sqrt(pi/2)erf(t/sqrt2).
// Lower-limit bracket is 2 only for r>=s; for s>r it is (s-2r)^2+2-s^2 (R5 bug fixed).
__device__ double lam_ball(double r, double s)
{
    const double C     = 0.063493635934241;      // (2*pi)^{-3/2}
    const double SQ2PI = 2.5066282746310002;
    const double IS2   = 0.7071067811865476;
    double a = fabs(r - s), b = r + s;
    double amr = a - r;
    double coefA = amr * amr + 2.0 - s * s;      // == 2 when r >= s
    double I = 2.0 * exp(-0.5 * b * b) - coefA * exp(-0.5 * a * a)
             + r * SQ2PI * (erf(b * IS2) - erf(a * IS2));
    double M = C * (M_PI / r) * I;
    if (s > r) {   // shells t in [0, s-r] fully inside the ball
        double u = s - r;
        M += 4.0 * M_PI * C * (sqrt(0.5 * M_PI) * erf(u * IS2) - u * exp(-0.5 * u * u));
    }
    return (double)NPTS * M;
}

__global__ void gate_kernel(const float* __restrict__ pts, float* __restrict__ gates,
                            float* __restrict__ out)
{
    int i = blockIdx.x * 256 + threadIdx.x;
    if (i == 0) { out[0] = 0.0f; out[1] = 0.0f; }   // fold output zeroing in here
    double qx = pts[i * 3 + 0], qy = pts[i * 3 + 1], qz = pts[i * 3 + 2];
    double r = sqrt(qx * qx + qy * qy + qz * qz);
    if (r < 1e-6) r = 1e-6;
    double lo = 0.0, hi = 12.0;
    for (int it = 0; it < 24; ++it) {
        double mid = 0.5 * (lo + hi);
        if (lam_ball(r, mid) < LAMBDA_T) lo = mid; else hi = mid;
    }
    gates[i] = (float)(hi * hi);
}

// ---------- fp64 cyclic Jacobi 3x3 (verified R1-R5) ----------
__device__ __forceinline__ void jrot(double& app, double& aqq, double& apq,
                                     double& arp, double& arq,
                                     double& vp0, double& vq0,
                                     double& vp1, double& vq1,
                                     double& vp2, double& vq2)
{
    double g = apq;
    if (g == 0.0) return;
    double theta = (aqq - app) / (2.0 * g);
    double at = fabs(theta);
    double t = (at > 1.0e154) ? (0.5 / theta)
                              : (copysign(1.0, theta) / (at + sqrt(theta * theta + 1.0)));
    double c = 1.0 / sqrt(t * t + 1.0);
    double s = t * c;
    double tau = s / (1.0 + c);
    app -= t * g;
    aqq += t * g;
    apq = 0.0;
    double rp = arp, rq = arq;
    arp = rp - s * (rq + tau * rp);
    arq = rq + s * (rp - tau * rq);
    double p0 = vp0, q0 = vq0;
    vp0 = p0 - s * (q0 + tau * p0); vq0 = q0 + s * (p0 - tau * q0);
    double p1 = vp1, q1 = vq1;
    vp1 = p1 - s * (q1 + tau * p1); vq1 = q1 + s * (p1 - tau * q1);
    double p2 = vp2, q2 = vq2;
    vp2 = p2 - s * (q2 + tau * p2); vq2 = q2 + s * (p2 - tau * q2);
}

__device__ __forceinline__ void eig3(double a00, double a11, double a22,
                                     double a01, double a02, double a12,
                                     double& nx, double& ny, double& nz,
                                     double& lmin, double& lsum)
{
    double v00 = 1, v01 = 0, v02 = 0;
    double v10 = 0, v11 = 1, v12 = 0;
    double v20 = 0, v21 = 0, v22 = 1;
    double scale = fabs(a00) + fabs(a11) + fabs(a22) + fabs(a01) + fabs(a02) + fabs(a12);
    if (scale > 0.0) {
        for (int sweep = 0; sweep < 6; ++sweep) {
            double off = fabs(a01) + fabs(a02) + fabs(a12);
            if (off <= scale * 1e-15) break;
            jrot(a00, a11, a01, a02, a12, v00, v01, v10, v11, v20, v21);
            jrot(a00, a22, a02, a01, a12, v00, v02, v10, v12, v20, v22);
            jrot(a11, a22, a12, a01, a02, v01, v02, v11, v12, v21, v22);
        }
    }
    lsum = a00 + a11 + a22;
    lmin = a00; nx = v00; ny = v10; nz = v20;
    if (a11 < lmin) { lmin = a11; nx = v01; ny = v11; nz = v21; }
    if (a22 < lmin) { lmin = a22; nx = v02; ny = v12; nz = v22; }
}

// u32 key: (d2 float bits, low 13 mantissa bits cleared) | idx(13b). Ties -> lower idx.
__device__ __forceinline__ unsigned mkkey(float d2, unsigned idx) {
    return (__float_as_uint(d2) & 0xFFFFE000u) | idx;
}

// Caller guarantees key < L[15]. Sorted-ascending bubble (v_min/v_max pairs).
__device__ __forceinline__ void insert16(unsigned key, unsigned* L)
{
    L[KNN - 1] = key;
    #pragma unroll
    for (int m = KNN - 1; m >= 1; --m) {
        unsigned a = L[m - 1], b = L[m];
        L[m - 1] = min(a, b);
        L[m]     = max(a, b);
    }
}

__device__ __forceinline__ float rfl(float x) {
    return __int_as_float(__builtin_amdgcn_readfirstlane(__float_as_int(x)));
}
__device__ __forceinline__ unsigned mbcnt64(unsigned long long m) {
    return __builtin_amdgcn_mbcnt_hi((unsigned)(m >> 32),
           __builtin_amdgcn_mbcnt_lo((unsigned)m, 0u));
}

// Block = 256 threads, 64 queries. Phase A: each wave filters all 8192 candidates
// (lane = candidate) against its 16 queries (SGPR-resident), ballot-compacting
// survivor indices into LDS. Phase B: wave0 = exact top-16 from survivors
// (+margin check + exact fallback) + fp64 cov/eig; waves1/2 = patch kNN + eig.
__global__ void __launch_bounds__(256)
spl_main(const float* __restrict__ pts, const float* __restrict__ gates,
         float* __restrict__ out)
{
    __shared__ float4 tile4[TILE];                 // 16 KB candidate tile (x,y,z,0.5|c|^2)
    __shared__ float4 pbuf4[PTCH];                 // 4 KB own patch
    __shared__ unsigned short surv[NQ * SSTRIDE];  // 16.25 KB survivor indices
    __shared__ unsigned cnts[NQ];                  // 256 B survivor counts
    __shared__ unsigned pListBuf[NQ * KNN];        // 4 KB wave2 patch half-list
    __shared__ double xbuf[NQ * 4];                // 2 KB patch normal+sv

    const int t = threadIdx.x;
    const int w = t >> 6;
    const int lane = t & 63;
    const int p = blockIdx.x;
    const int quarter = blockIdx.y;
    const int b = blockIdx.z;

    const float* base = pts + (size_t)b * (NPTS * 3);
    const int qbase = p * PTCH + quarter * NQ;

    // Stage own patch into padded LDS (read by waves1/2 after B1).
    {
        const float* src = base + p * (PTCH * 3);
        float* dst = (float*)pbuf4;
        #pragma unroll
        for (int s = 0; s < 3; ++s) {
            int f = t + s * 256;
            int j = f / 3;
            int c = f - 3 * j;
            dst[j * 4 + c] = src[f];
        }
    }

    // This wave's 16 filter-queries: wave-uniform coords + thresholds in SGPRs.
    float sqx[16], sqy[16], sqz[16], shq[16];
    unsigned scnt[16];
    #pragma unroll
    for (int u = 0; u < 16; ++u) {
        int qi = qbase + w * 16 + u;
        float x = base[qi * 3 + 0], y = base[qi * 3 + 1], z = base[qi * 3 + 2];
        float gg = gates ? gates[b * NPTS + qi] : 3.0e38f;
        sqx[u] = rfl(x); sqy[u] = rfl(y); sqz[u] = rfl(z);
        shq[u] = rfl(0.5f * (gg - (x * x + y * y + z * z)));
        scnt[u] = 0;
    }

    // ---- Phase A: ballot-compacted gate filter ----
    #pragma unroll 1
    for (int t8 = 0; t8 < NPTS / TILE; ++t8) {
        __syncthreads();
        const int tb = t8 * TILE;
        #pragma unroll
        for (int k = 0; k < 4; ++k) {
            int ci = tb + k * 256 + t;
            float x = base[ci * 3 + 0], y = base[ci * 3 + 1], z = base[ci * 3 + 2];
            tile4[k * 256 + t] = make_float4(x, y, z, 0.5f * (x * x + y * y + z * z));
        }
        __syncthreads();
        #pragma unroll 1
        for (int it = 0; it < TILE / 64; ++it) {
            float4 c = tile4[it * 64 + lane];          // contiguous b128, conflict-free
            unsigned gidx = (unsigned)(tb + it * 64 + lane);
            #pragma unroll
            for (int u = 0; u < 16; ++u) {
                // d2 < g  <=>  0.5|c|^2 - q.c < 0.5(g - |q|^2)
                float tt = fmaf(-c.x, sqx[u], c.w);
                tt = fmaf(-c.y, sqy[u], tt);
                tt = fmaf(-c.z, sqz[u], tt);
                bool pass = tt < shq[u];
                unsigned long long m = __ballot(pass);
                if (m) {
                    unsigned pre = mbcnt64(m);
                    if (pass) {
                        unsigned slot = scnt[u] + pre;
                        slot = slot < (SSTRIDE - 1) ? slot : (SSTRIDE - 1);
                        surv[(w * 16 + u) * SSTRIDE + slot] = (unsigned short)gidx;
                    }
                    scnt[u] += (unsigned)__popcll(m);  // wave-uniform (SGPR)
                }
            }
        }
    }
    if (lane == 0) {
        #pragma unroll
        for (int u = 0; u < 16; ++u) cnts[w * 16 + u] = scnt[u];
    }
    __syncthreads();   // B1

    // ---- Phase B ----
    double ngx = 0, ngy = 0, ngz = 0, svg = 0;
    unsigned pl[KNN];
    float pqx = 0.f, pqy = 0.f, pqz = 0.f;
    if (w <= 2) {
        int qi = qbase + lane;
        pqx = base[qi * 3 + 0];
        pqy = base[qi * 3 + 1];
        pqz = base[qi * 3 + 2];
    }

    if (w == 0) {
        const float g = gates ? gates[b * NPTS + qbase + lane] : 3.0e38f;
        unsigned gl[KNN];
        #pragma unroll
        for (int m = 0; m < KNN; ++m) gl[m] = 0xFFFFFFFFu;
        unsigned myCnt = cnts[lane];
        bool invalid = (myCnt < KNN) || (myCnt > SSTRIDE);
        if (!invalid) {
            #pragma unroll 1
            for (unsigned m = 0; m < myCnt; ++m) {
                unsigned idx = surv[lane * SSTRIDE + m];
                float cx = base[idx * 3 + 0];
                float cy = base[idx * 3 + 1];
                float cz = base[idx * 3 + 2];
                float dx = pqx - cx, dy = pqy - cy, dz = pqz - cz;
                float d2 = dx * dx + dy * dy + dz * dz;   // reference-form d2
                unsigned k = mkkey(d2, idx);
                if (k < gl[KNN - 1]) insert16(k, gl);
            }
            // margin check: all filtered-out points provably outside 16th bucket
            float upper = __uint_as_float((gl[KNN - 1] & 0xFFFFE000u) + 0x2000u);
            invalid = !(upper < g * 0.999f - 1e-5f);
        }
        if (__any(invalid ? 1 : 0)) {
            if (invalid) {   // exact fallback (P ~ 1e-12/query now)
                #pragma unroll
                for (int m = 0; m < KNN; ++m) gl[m] = 0xFFFFFFFFu;
                #pragma unroll 1
                for (int i = 0; i < NPTS; ++i) {
                    float cx = base[i * 3 + 0];
                    float cy = base[i * 3 + 1];
                    float cz = base[i * 3 + 2];
                    float dx = pqx - cx, dy = pqy - cy, dz = pqz - cz;
                    float d2 = dx * dx + dy * dy + dz * dz;
                    unsigned k = mkkey(d2, (unsigned)i);
                    if (k < gl[KNN - 1]) insert16(k, gl);
                }
            }
        }
        double c00 = 0, c11 = 0, c22 = 0, c01 = 0, c02 = 0, c12 = 0;
        const double qxd = pqx, qyd = pqy, qzd = pqz;
        #pragma unroll
        for (int m = 0; m < KNN; ++m) {
            int idx = (int)(gl[m] & 0x1FFFu);
            double dx = (double)base[idx * 3 + 0] - qxd;
            double dy = (double)base[idx * 3 + 1] - qyd;
            double dz = (double)base[idx * 3 + 2] - qzd;
            c00 += dx * dx; c11 += dy * dy; c22 += dz * dz;
            c01 += dx * dy; c02 += dx * dz; c12 += dy * dz;
        }
        double lmin, lsum;
        eig3(c00, c11, c22, c01, c02, c12, ngx, ngy, ngz, lmin, lsum);
        svg = lmin / lsum;
    } else if (w <= 2) {
        // Patch kNN half-scan (local indices), gated bubble over 128 candidates.
        #pragma unroll
        for (int m = 0; m < KNN; ++m) pl[m] = 0xFFFFFFFFu;
        const int c0r = (w == 1) ? 0 : 128;
        #pragma unroll 1
        for (int j = c0r; j < c0r + 128; ++j) {
            float4 c = pbuf4[j];
            float dx = pqx - c.x, dy = pqy - c.y, dz = pqz - c.z;
            float d2 = dx * dx + dy * dy + dz * dz;
            unsigned k = mkkey(d2, (unsigned)j);
            if (k < pl[KNN - 1]) insert16(k, pl);
        }
        if (w == 2) {
            #pragma unroll
            for (int m = 0; m < KNN; ++m) pListBuf[lane * KNN + m] = pl[m];
        }
    }
    __syncthreads();   // B2

    if (w == 1) {
        for (int m = 0; m < KNN; ++m) {
            unsigned key = pListBuf[lane * KNN + m];
            if (key >= pl[KNN - 1]) break;
            insert16(key, pl);
        }
        double c00 = 0, c11 = 0, c22 = 0, c01 = 0, c02 = 0, c12 = 0;
        const double qxd = pqx, qyd = pqy, qzd = pqz;
        #pragma unroll
        for (int m = 0; m < KNN; ++m) {
            int idx = (int)(pl[m] & 0x1FFFu);
            float4 cpt = pbuf4[idx];
            double dx = (double)cpt.x - qxd;
            double dy = (double)cpt.y - qyd;
            double dz = (double)cpt.z - qzd;
            c00 += dx * dx; c11 += dy * dy; c22 += dz * dz;
            c01 += dx * dy; c02 += dx * dz; c12 += dy * dz;
        }
        double nx, ny, nz, lmin, lsum;
        eig3(c00, c11, c22, c01, c02, c12, nx, ny, nz, lmin, lsum);
        xbuf[lane * 4 + 0] = nx;
        xbuf[lane * 4 + 1] = ny;
        xbuf[lane * 4 + 2] = nz;
        xbuf[lane * 4 + 3] = lmin / lsum;
    }
    __syncthreads();   // B3

    if (w == 0) {
        double npx = xbuf[lane * 4 + 0];
        double npy = xbuf[lane * 4 + 1];
        double npz = xbuf[lane * 4 + 2];
        double svp = xbuf[lane * 4 + 3];
        double dx = fabs(npx) - fabs(ngx);
        double dy = fabs(npy) - fabs(ngy);
        double dz = fabs(npz) - fabs(ngz);
        double ln  = sqrt(dx * dx + dy * dy + dz * dz);
        double ds  = svp - svg;
        double lsv = ds * ds;
        #pragma unroll
        for (int o = 32; o > 0; o >>= 1) {
            ln  += __shfl_down(ln, o);
            lsv += __shfl_down(lsv, o);
        }
        if (lane == 0) {
            const double inv = 1.0 / (double)(NBATCH * NPTS);
            atomicAdd(&out[0], (float)(ln * inv));
            atomicAdd(&out[1], (float)(lsv * inv));
        }
    }
}

__global__ void zero2_kernel(float* out) { out[0] = 0.0f; out[1] = 0.0f; }

extern "C" void kernel_launch(void* const* d_in, const int* in_sizes, int n_in,
                              void* d_out, int out_size, void* d_ws, size_t ws_size,
                              hipStream_t stream)
{
    const float* pts = (const float*)d_in[0];
    float* out = (float*)d_out;
    const size_t gate_bytes = (size_t)(NBATCH * NPTS) * sizeof(float);
    float* gates = (ws_size >= gate_bytes) ? (float*)d_ws : nullptr;

    if (gates) {
        hipLaunchKernelGGL(gate_kernel, dim3(NBATCH * NPTS / 256), dim3(256), 0, stream,
                           pts, gates, out);
    } else {
        hipLaunchKernelGGL(zero2_kernel, dim3(1), dim3(1), 0, stream, out);
    }
    dim3 grid(NPATCH, 4, NBATCH);
    hipLaunchKernelGGL(spl_main, grid, dim3(256), 0, stream, pts, gates, out);
}

// Round 7
// 185.455 us; speedup vs baseline: 5.8812x; 1.1454x over previous
//
#include <hip/hip_runtime.h>
#include <math.h>

#define KNN 16
#define NPTS 8192
#define PTCH 256
#define NPATCH 32
#define NBATCH 4
#define NQ 64            // queries per block (quarter patch)
#define TILE 512         // candidates per LDS tile
#define SSTRIDE 130      // survivor slots/query (mean 64, +8sigma)
#define LAMBDA_T 64.0f   // target E[survivors]/query

__global__ void zero2_kernel(float* out) { out[0] = 0.0f; out[1] = 0.0f; }

// E[#points within distance s of a query at radius r], N iid N(0,I3). fp32.
// Cap-shell integral; lower-limit bracket (a-r)^2+2-s^2 (== 2 for r>=s; R5 bug fixed).
// Heuristic only: exactness is guaranteed by phase-B margin check + fallback.
__device__ __forceinline__ float lam_f(float r, float s)
{
    const float C     = 0.063493636f;    // (2*pi)^{-3/2}
    const float SQ2PI = 2.5066283f;
    const float IS2   = 0.70710678f;
    float a = fabsf(r - s), b = r + s;
    float amr = a - r;
    float coefA = amr * amr + 2.f - s * s;
    float I = 2.f * __expf(-0.5f * b * b) - coefA * __expf(-0.5f * a * a)
            + r * SQ2PI * (erff(b * IS2) - erff(a * IS2));
    float M = C * (3.14159265f / r) * I;
    if (s > r) {   // shells fully inside the ball
        float u = s - r;
        M += 12.566371f * C * (1.2533141f * erff(u * IS2) - u * __expf(-0.5f * u * u));
    }
    return (float)NPTS * M;
}

// ---------- fp64 cyclic Jacobi 3x3 (verified R1-R6) ----------
__device__ __forceinline__ void jrot(double& app, double& aqq, double& apq,
                                     double& arp, double& arq,
                                     double& vp0, double& vq0,
                                     double& vp1, double& vq1,
                                     double& vp2, double& vq2)
{
    double g = apq;
    if (g == 0.0) return;
    double theta = (aqq - app) / (2.0 * g);
    double at = fabs(theta);
    double t = (at > 1.0e154) ? (0.5 / theta)
                              : (copysign(1.0, theta) / (at + sqrt(theta * theta + 1.0)));
    double c = 1.0 / sqrt(t * t + 1.0);
    double s = t * c;
    double tau = s / (1.0 + c);
    app -= t * g;
    aqq += t * g;
    apq = 0.0;
    double rp = arp, rq = arq;
    arp = rp - s * (rq + tau * rp);
    arq = rq + s * (rp - tau * rq);
    double p0 = vp0, q0 = vq0;
    vp0 = p0 - s * (q0 + tau * p0); vq0 = q0 + s * (p0 - tau * q0);
    double p1 = vp1, q1 = vq1;
    vp1 = p1 - s * (q1 + tau * p1); vq1 = q1 + s * (p1 - tau * q1);
    double p2 = vp2, q2 = vq2;
    vp2 = p2 - s * (q2 + tau * p2); vq2 = q2 + s * (p2 - tau * q2);
}

__device__ __forceinline__ void eig3(double a00, double a11, double a22,
                                     double a01, double a02, double a12,
                                     double& nx, double& ny, double& nz,
                                     double& lmin, double& lsum)
{
    double v00 = 1, v01 = 0, v02 = 0;
    double v10 = 0, v11 = 1, v12 = 0;
    double v20 = 0, v21 = 0, v22 = 1;
    double scale = fabs(a00) + fabs(a11) + fabs(a22) + fabs(a01) + fabs(a02) + fabs(a12);
    if (scale > 0.0) {
        for (int sweep = 0; sweep < 6; ++sweep) {
            double off = fabs(a01) + fabs(a02) + fabs(a12);
            if (off <= scale * 1e-15) break;
            jrot(a00, a11, a01, a02, a12, v00, v01, v10, v11, v20, v21);
            jrot(a00, a22, a02, a01, a12, v00, v02, v10, v12, v20, v22);
            jrot(a11, a22, a12, a01, a02, v01, v02, v11, v12, v21, v22);
        }
    }
    lsum = a00 + a11 + a22;
    lmin = a00; nx = v00; ny = v10; nz = v20;
    if (a11 < lmin) { lmin = a11; nx = v01; ny = v11; nz = v21; }
    if (a22 < lmin) { lmin = a22; nx = v02; ny = v12; nz = v22; }
}

// u32 key: (d2 float bits, low 13 mantissa bits cleared) | idx(13b). Ties -> lower idx.
__device__ __forceinline__ unsigned mkkey(float d2, unsigned idx) {
    return (__float_as_uint(d2) & 0xFFFFE000u) | idx;
}

// Caller guarantees key < L[15]. Sorted-ascending bubble (v_min/v_max pairs).
__device__ __forceinline__ void insert16(unsigned key, unsigned* L)
{
    L[KNN - 1] = key;
    #pragma unroll
    for (int m = KNN - 1; m >= 1; --m) {
        unsigned a = L[m - 1], b = L[m];
        L[m - 1] = min(a, b);
        L[m]     = max(a, b);
    }
}

__device__ __forceinline__ float rfl(float x) {
    return __int_as_float(__builtin_amdgcn_readfirstlane(__float_as_int(x)));
}
__device__ __forceinline__ unsigned mbcnt64(unsigned long long m) {
    return __builtin_amdgcn_mbcnt_hi((unsigned)(m >> 32),
           __builtin_amdgcn_mbcnt_lo((unsigned)m, 0u));
}

// Block = 256 threads, 64 queries. Gates computed in-kernel (fp32 bisection).
// Phase A: each wave ballot-filters all 8192 candidates against its 16 queries.
// Phase B: waves0+3 split the survivor top-16 scan; waves1/2 do patch kNN halves.
__global__ void __launch_bounds__(256, 4)
spl_main(const float* __restrict__ pts, float* __restrict__ out)
{
    __shared__ float4 tile4[TILE];                 // 8 KB candidate tile
    __shared__ float4 pbuf4[PTCH];                 // 4 KB own patch
    __shared__ unsigned short surv[NQ * SSTRIDE];  // 16.25 KB survivor indices
    __shared__ unsigned cnts[NQ];                  // 256 B
    __shared__ float gbuf[NQ];                     // 256 B gates
    __shared__ unsigned pListBuf[NQ * KNN];        // 4 KB wave2 patch half-list
    __shared__ double xbuf[NQ * 4];                // 2 KB patch normal+sv
    // ~35 KB -> 4 blocks/CU

    const int t = threadIdx.x;
    const int w = t >> 6;
    const int lane = t & 63;
    const int p = blockIdx.x;
    const int quarter = blockIdx.y;
    const int b = blockIdx.z;

    const float* base = pts + (size_t)b * (NPTS * 3);
    const int qbase = p * PTCH + quarter * NQ;

    // Stage own patch into padded LDS.
    {
        const float* src = base + p * (PTCH * 3);
        float* dst = (float*)pbuf4;
        #pragma unroll
        for (int s = 0; s < 3; ++s) {
            int f = t + s * 256;
            int j = f / 3;
            int c = f - 3 * j;
            dst[j * 4 + c] = src[f];
        }
    }
    // Gates for this block's 64 queries (fp32 bisection, threads 0..63).
    if (t < NQ) {
        int qi = qbase + t;
        float x = base[qi * 3 + 0], y = base[qi * 3 + 1], z = base[qi * 3 + 2];
        float r = fmaxf(sqrtf(x * x + y * y + z * z), 0.01f);
        float lo = 0.f, hi = 12.f;
        #pragma unroll 1
        for (int it = 0; it < 16; ++it) {
            float mid = 0.5f * (lo + hi);
            if (lam_f(r, mid) < LAMBDA_T) lo = mid; else hi = mid;
        }
        gbuf[t] = hi * hi;
    }
    __syncthreads();

    // This wave's 16 filter-queries: wave-uniform coords + thresholds in SGPRs.
    float sqx[16], sqy[16], sqz[16], shq[16];
    unsigned scnt[16];
    #pragma unroll
    for (int u = 0; u < 16; ++u) {
        float4 qv = pbuf4[quarter * NQ + w * 16 + u];
        float gg = gbuf[w * 16 + u];
        sqx[u] = rfl(qv.x); sqy[u] = rfl(qv.y); sqz[u] = rfl(qv.z);
        shq[u] = rfl(0.5f * (gg - (qv.x * qv.x + qv.y * qv.y + qv.z * qv.z)));
        scnt[u] = 0;
    }

    // ---- Phase A: ballot-compacted gate filter ----
    #pragma unroll 1
    for (int tb = 0; tb < NPTS; tb += TILE) {
        __syncthreads();
        {
            const float* src = base + tb * 3;
            float* dst = (float*)tile4;
            #pragma unroll
            for (int s = 0; s < 6; ++s) {
                int f = t + s * 256;
                int j = f / 3;
                int c = f - 3 * j;
                dst[j * 4 + c] = src[f];
            }
        }
        __syncthreads();
        float4 c = tile4[lane];
        #pragma unroll 1
        for (int it = 0; it < TILE / 64; ++it) {
            float4 cn = tile4[min(it + 1, TILE / 64 - 1) * 64 + lane];  // prefetch
            float hn = 0.5f * (c.x * c.x + c.y * c.y + c.z * c.z);
            unsigned gidx = (unsigned)(tb + it * 64 + lane);
            #pragma unroll
            for (int u = 0; u < 16; ++u) {
                // d2 < g  <=>  0.5|c|^2 - q.c < 0.5(g - |q|^2)
                float tt = fmaf(-c.x, sqx[u], hn);
                tt = fmaf(-c.y, sqy[u], tt);
                tt = fmaf(-c.z, sqz[u], tt);
                bool pass = tt < shq[u];
                unsigned long long m = __ballot(pass);
                if (m) {
                    unsigned pre = mbcnt64(m);
                    if (pass) {
                        unsigned slot = min(scnt[u] + pre, (unsigned)(SSTRIDE - 1));
                        surv[(w * 16 + u) * SSTRIDE + slot] = (unsigned short)gidx;
                    }
                    scnt[u] += (unsigned)__popcll(m);  // wave-uniform (SGPR)
                }
            }
            c = cn;
        }
    }
    if (lane == 0) {
        #pragma unroll
        for (int u = 0; u < 16; ++u) cnts[w * 16 + u] = scnt[u];
    }
    __syncthreads();   // B1

    // ---- Phase B ----
    unsigned* w3buf = (unsigned*)tile4;   // tile4 dead after phase A
    double ngx = 0, ngy = 0, ngz = 0, svg = 0;
    unsigned pl[KNN];
    float4 qv = pbuf4[quarter * NQ + lane];
    const float pqx = qv.x, pqy = qv.y, pqz = qv.z;

    unsigned gl[KNN];
    #pragma unroll
    for (int m = 0; m < KNN; ++m) gl[m] = 0xFFFFFFFFu;
    bool valid = false;

    if (w == 0 || w == 3) {
        unsigned myCnt = cnts[lane];
        valid = (myCnt >= KNN) && (myCnt <= SSTRIDE);
        if (valid) {
            unsigned h = (myCnt + 1) >> 1;
            unsigned m0 = (w == 0) ? 0u : h;
            unsigned m1 = (w == 0) ? h : myCnt;
            #pragma unroll 1
            for (unsigned m = m0; m < m1; ++m) {
                unsigned idx = surv[lane * SSTRIDE + m];
                float cx = base[idx * 3 + 0];
                float cy = base[idx * 3 + 1];
                float cz = base[idx * 3 + 2];
                float dx = pqx - cx, dy = pqy - cy, dz = pqz - cz;
                float d2 = dx * dx + dy * dy + dz * dz;   // reference-form d2
                unsigned k = mkkey(d2, idx);
                if (k < gl[KNN - 1]) insert16(k, gl);
            }
        }
        if (w == 3) {
            #pragma unroll
            for (int m = 0; m < KNN; ++m) w3buf[lane * KNN + m] = gl[m];
        }
    } else {
        // Patch kNN half-scan (local indices), gated bubble over 128 candidates.
        #pragma unroll
        for (int m = 0; m < KNN; ++m) pl[m] = 0xFFFFFFFFu;
        const int c0r = (w == 1) ? 0 : 128;
        #pragma unroll 1
        for (int j = c0r; j < c0r + 128; ++j) {
            float4 c = pbuf4[j];
            float dx = pqx - c.x, dy = pqy - c.y, dz = pqz - c.z;
            float d2 = dx * dx + dy * dy + dz * dz;
            unsigned k = mkkey(d2, (unsigned)j);
            if (k < pl[KNN - 1]) insert16(k, pl);
        }
        if (w == 2) {
            #pragma unroll
            for (int m = 0; m < KNN; ++m) pListBuf[lane * KNN + m] = pl[m];
        }
    }
    __syncthreads();   // B2

    if (w == 0) {
        const float g = gbuf[lane];
        if (valid) {
            for (int m = 0; m < KNN; ++m) {   // merge wave3's sorted half-list
                unsigned key = w3buf[lane * KNN + m];
                if (key >= gl[KNN - 1]) break;
                insert16(key, gl);
            }
            // margin check: all filtered-out points provably outside 16th bucket
            float upper = __uint_as_float((gl[KNN - 1] & 0xFFFFE000u) + 0x2000u);
            valid = (upper < g * 0.999f - 1e-5f);
        }
        if (__any(valid ? 0 : 1)) {
            if (!valid) {   // exact fallback (P ~ 1e-12/query)
                #pragma unroll
                for (int m = 0; m < KNN; ++m) gl[m] = 0xFFFFFFFFu;
                #pragma unroll 1
                for (int i = 0; i < NPTS; ++i) {
                    float cx = base[i * 3 + 0];
                    float cy = base[i * 3 + 1];
                    float cz = base[i * 3 + 2];
                    float dx = pqx - cx, dy = pqy - cy, dz = pqz - cz;
                    float d2 = dx * dx + dy * dy + dz * dz;
                    unsigned k = mkkey(d2, (unsigned)i);
                    if (k < gl[KNN - 1]) insert16(k, gl);
                }
            }
        }
        double c00 = 0, c11 = 0, c22 = 0, c01 = 0, c02 = 0, c12 = 0;
        const double qxd = pqx, qyd = pqy, qzd = pqz;
        #pragma unroll
        for (int m = 0; m < KNN; ++m) {
            int idx = (int)(gl[m] & 0x1FFFu);
            double dx = (double)base[idx * 3 + 0] - qxd;
            double dy = (double)base[idx * 3 + 1] - qyd;
            double dz = (double)base[idx * 3 + 2] - qzd;
            c00 += dx * dx; c11 += dy * dy; c22 += dz * dz;
            c01 += dx * dy; c02 += dx * dz; c12 += dy * dz;
        }
        double lmin, lsum;
        eig3(c00, c11, c22, c01, c02, c12, ngx, ngy, ngz, lmin, lsum);
        svg = lmin / lsum;
    } else if (w == 1) {
        for (int m = 0; m < KNN; ++m) {
            unsigned key = pListBuf[lane * KNN + m];
            if (key >= pl[KNN - 1]) break;
            insert16(key, pl);
        }
        double c00 = 0, c11 = 0, c22 = 0, c01 = 0, c02 = 0, c12 = 0;
        const double qxd = pqx, qyd = pqy, qzd = pqz;
        #pragma unroll
        for (int m = 0; m < KNN; ++m) {
            int idx = (int)(pl[m] & 0x1FFFu);
            float4 cpt = pbuf4[idx];
            double dx = (double)cpt.x - qxd;
            double dy = (double)cpt.y - qyd;
            double dz = (double)cpt.z - qzd;
            c00 += dx * dx; c11 += dy * dy; c22 += dz * dz;
            c01 += dx * dy; c02 += dx * dz; c12 += dy * dz;
        }
        double nx, ny, nz, lmin, lsum;
        eig3(c00, c11, c22, c01, c02, c12, nx, ny, nz, lmin, lsum);
        xbuf[lane * 4 + 0] = nx;
        xbuf[lane * 4 + 1] = ny;
        xbuf[lane * 4 + 2] = nz;
        xbuf[lane * 4 + 3] = lmin / lsum;
    }
    __syncthreads();   // B3

    if (w == 0) {
        double npx = xbuf[lane * 4 + 0];
        double npy = xbuf[lane * 4 + 1];
        double npz = xbuf[lane * 4 + 2];
        double svp = xbuf[lane * 4 + 3];
        double dx = fabs(npx) - fabs(ngx);
        double dy = fabs(npy) - fabs(ngy);
        double dz = fabs(npz) - fabs(ngz);
        double ln  = sqrt(dx * dx + dy * dy + dz * dz);
        double ds  = svp - svg;
        double lsv = ds * ds;
        #pragma unroll
        for (int o = 32; o > 0; o >>= 1) {
            ln  += __shfl_down(ln, o);
            lsv += __shfl_down(lsv, o);
        }
        if (lane == 0) {
            const double inv = 1.0 / (double)(NBATCH * NPTS);
            atomicAdd(&out[0], (float)(ln * inv));
            atomicAdd(&out[1], (float)(lsv * inv));
        }
    }
}

extern "C" void kernel_launch(void* const* d_in, const int* in_sizes, int n_in,
                              void* d_out, int out_size, void* d_ws, size_t ws_size,
                              hipStream_t stream)
{
    const float* pts = (const float*)d_in[0];
    float* out = (float*)d_out;
    hipLaunchKernelGGL(zero2_kernel, dim3(1), dim3(1), 0, stream, out);
    dim3 grid(NPATCH, 4, NBATCH);
    hipLaunchKernelGGL(spl_main, grid, dim3(256), 0, stream, pts, out);
}

// Round 8
// 162.211 us; speedup vs baseline: 6.7239x; 1.1433x over previous
//
#include <hip/hip_runtime.h>
#include <math.h>

#define KNN 16
#define NPTS 8192
#define PTCH 256
#define NPATCH 32
#define NBATCH 4
#define NQ 32            // queries per block (eighth patch)
#define TILE 1024        // candidates per LDS tile
#define SSTRIDE 130      // survivor slots/query (mean 64, +8sigma)
#define LAMBDA_T 64.0f   // target E[survivors]/query

__global__ void zero2_kernel(float* out) { out[0] = 0.0f; out[1] = 0.0f; }

// E[#points within distance s of a query at radius r], N iid N(0,I3). fp32.
// Heuristic only: exactness guaranteed by phase-B margin check + fallback.
__device__ __forceinline__ float lam_f(float r, float s)
{
    const float C     = 0.063493636f;    // (2*pi)^{-3/2}
    const float SQ2PI = 2.5066283f;
    const float IS2   = 0.70710678f;
    float a = fabsf(r - s), b = r + s;
    float amr = a - r;
    float coefA = amr * amr + 2.f - s * s;   // == 2 when r >= s (R5 bug fixed)
    float I = 2.f * __expf(-0.5f * b * b) - coefA * __expf(-0.5f * a * a)
            + r * SQ2PI * (erff(b * IS2) - erff(a * IS2));
    float M = C * (3.14159265f / r) * I;
    if (s > r) {
        float u = s - r;
        M += 12.566371f * C * (1.2533141f * erff(u * IS2) - u * __expf(-0.5f * u * u));
    }
    return (float)NPTS * M;
}

// ---------- fp64 cyclic Jacobi 3x3 (verified R1-R7) ----------
__device__ __forceinline__ void jrot(double& app, double& aqq, double& apq,
                                     double& arp, double& arq,
                                     double& vp0, double& vq0,
                                     double& vp1, double& vq1,
                                     double& vp2, double& vq2)
{
    double g = apq;
    if (g == 0.0) return;
    double theta = (aqq - app) / (2.0 * g);
    double at = fabs(theta);
    double t = (at > 1.0e154) ? (0.5 / theta)
                              : (copysign(1.0, theta) / (at + sqrt(theta * theta + 1.0)));
    double c = 1.0 / sqrt(t * t + 1.0);
    double s = t * c;
    double tau = s / (1.0 + c);
    app -= t * g;
    aqq += t * g;
    apq = 0.0;
    double rp = arp, rq = arq;
    arp = rp - s * (rq + tau * rp);
    arq = rq + s * (rp - tau * rq);
    double p0 = vp0, q0 = vq0;
    vp0 = p0 - s * (q0 + tau * p0); vq0 = q0 + s * (p0 - tau * q0);
    double p1 = vp1, q1 = vq1;
    vp1 = p1 - s * (q1 + tau * p1); vq1 = q1 + s * (p1 - tau * q1);
    double p2 = vp2, q2 = vq2;
    vp2 = p2 - s * (q2 + tau * p2); vq2 = q2 + s * (p2 - tau * q2);
}

__device__ __forceinline__ void eig3(double a00, double a11, double a22,
                                     double a01, double a02, double a12,
                                     double& nx, double& ny, double& nz,
                                     double& lmin, double& lsum)
{
    double v00 = 1, v01 = 0, v02 = 0;
    double v10 = 0, v11 = 1, v12 = 0;
    double v20 = 0, v21 = 0, v22 = 1;
    double scale = fabs(a00) + fabs(a11) + fabs(a22) + fabs(a01) + fabs(a02) + fabs(a12);
    if (scale > 0.0) {
        for (int sweep = 0; sweep < 6; ++sweep) {
            double off = fabs(a01) + fabs(a02) + fabs(a12);
            if (off <= scale * 1e-15) break;
            jrot(a00, a11, a01, a02, a12, v00, v01, v10, v11, v20, v21);
            jrot(a00, a22, a02, a01, a12, v00, v02, v10, v12, v20, v22);
            jrot(a11, a22, a12, a01, a02, v01, v02, v11, v12, v21, v22);
        }
    }
    lsum = a00 + a11 + a22;
    lmin = a00; nx = v00; ny = v10; nz = v20;
    if (a11 < lmin) { lmin = a11; nx = v01; ny = v11; nz = v21; }
    if (a22 < lmin) { lmin = a22; nx = v02; ny = v12; nz = v22; }
}

// u32 key: (d2 float bits, low 13 mantissa bits cleared) | idx(13b). Ties -> lower idx.
__device__ __forceinline__ unsigned mkkey(float d2, unsigned idx) {
    return (__float_as_uint(d2) & 0xFFFFE000u) | idx;
}

// Caller guarantees key < L[15]. Sorted-ascending bubble (v_min/v_max pairs).
__device__ __forceinline__ void insert16(unsigned key, unsigned* L)
{
    L[KNN - 1] = key;
    #pragma unroll
    for (int m = KNN - 1; m >= 1; --m) {
        unsigned a = L[m - 1], b = L[m];
        L[m - 1] = min(a, b);
        L[m]     = max(a, b);
    }
}

// Snapshot-based butterfly merge of sorted 16-lists across lanes h = lane&3.
// Snapshot (all shfls) happens before any insert so both partners see the
// pre-merge lists; after steps 1,2 all 4 lanes hold the merged top-16.
__device__ __forceinline__ void merge4(unsigned* L, int lane)
{
    #pragma unroll
    for (int step = 1; step <= 2; step <<= 1) {
        unsigned tmp[KNN];
        #pragma unroll
        for (int m = 0; m < KNN; ++m) tmp[m] = __shfl(L[m], lane ^ step, 64);
        for (int m = 0; m < KNN; ++m) {
            if (tmp[m] >= L[KNN - 1]) break;
            insert16(tmp[m], L);
        }
    }
}

__device__ __forceinline__ float rfl(float x) {
    return __int_as_float(__builtin_amdgcn_readfirstlane(__float_as_int(x)));
}
__device__ __forceinline__ unsigned mbcnt64(unsigned long long m) {
    return __builtin_amdgcn_mbcnt_hi((unsigned)(m >> 32),
           __builtin_amdgcn_mbcnt_lo((unsigned)m, 0u));
}

// Block = 256 threads, 32 queries (eighth patch); grid 1024 -> 4 blocks/CU.
// Phase A: each wave ballot-filters all 8192 candidates against its 8 queries.
// Phase B: waves0/1 = global top-16 (4 lanes/query) + fp64 cov/eig;
//          waves2/3 = patch kNN (4 lanes/query x 64 pts) + fp64 cov/eig.
__global__ void __launch_bounds__(256, 4)
spl_main(const float* __restrict__ pts, float* __restrict__ out)
{
    __shared__ float4 tile4[TILE];                 // 16 KB candidate tile
    __shared__ float4 pbuf4[PTCH];                 // 4 KB own patch
    __shared__ unsigned short surv[NQ * SSTRIDE];  // 8.3 KB survivor indices
    __shared__ unsigned cnts[NQ];                  // 128 B
    __shared__ float gbuf[NQ];                     // 128 B gates
    __shared__ double xbuf[NQ * 4];                // 1 KB patch normal+sv
    __shared__ double rb[4];                       // partials
    // ~30 KB -> 4 blocks/CU (grid-limited at 4)

    const int t = threadIdx.x;
    const int w = t >> 6;
    const int lane = t & 63;
    const int p = blockIdx.x;
    const int eighth = blockIdx.y;
    const int b = blockIdx.z;

    const float* base = pts + (size_t)b * (NPTS * 3);
    const int qbase = p * PTCH + eighth * NQ;

    // Stage own patch into padded LDS.
    {
        const float* src = base + p * (PTCH * 3);
        float* dst = (float*)pbuf4;
        #pragma unroll
        for (int s = 0; s < 3; ++s) {
            int f = t + s * 256;
            int j = f / 3;
            int c = f - 3 * j;
            dst[j * 4 + c] = src[f];
        }
    }
    // Gates for this block's 32 queries (fp32 bisection, threads 0..31).
    if (t < NQ) {
        int qi = qbase + t;
        float x = base[qi * 3 + 0], y = base[qi * 3 + 1], z = base[qi * 3 + 2];
        float r = fmaxf(sqrtf(x * x + y * y + z * z), 0.01f);
        float lo = 0.f, hi = 12.f;
        #pragma unroll 1
        for (int it = 0; it < 16; ++it) {
            float mid = 0.5f * (lo + hi);
            if (lam_f(r, mid) < LAMBDA_T) lo = mid; else hi = mid;
        }
        gbuf[t] = hi * hi;
    }
    __syncthreads();

    // This wave's 8 filter-queries: wave-uniform coords + thresholds in SGPRs.
    float sqx[8], sqy[8], sqz[8], shq[8];
    unsigned scnt[8];
    #pragma unroll
    for (int u = 0; u < 8; ++u) {
        float4 qv = pbuf4[eighth * NQ + w * 8 + u];
        float gg = gbuf[w * 8 + u];
        sqx[u] = rfl(qv.x); sqy[u] = rfl(qv.y); sqz[u] = rfl(qv.z);
        shq[u] = rfl(0.5f * (gg - (qv.x * qv.x + qv.y * qv.y + qv.z * qv.z)));
        scnt[u] = 0;
    }

    // ---- Phase A: ballot-compacted gate filter ----
    #pragma unroll 1
    for (int tb = 0; tb < NPTS; tb += TILE) {
        __syncthreads();
        {
            const float* src = base + tb * 3;
            float* dst = (float*)tile4;
            #pragma unroll
            for (int s = 0; s < 12; ++s) {
                int f = t + s * 256;
                int j = f / 3;
                int c = f - 3 * j;
                dst[j * 4 + c] = src[f];
            }
        }
        __syncthreads();
        float4 c = tile4[lane];
        #pragma unroll 1
        for (int it = 0; it < TILE / 64; ++it) {
            float4 cn = tile4[min(it + 1, TILE / 64 - 1) * 64 + lane];  // prefetch
            float hn = 0.5f * (c.x * c.x + c.y * c.y + c.z * c.z);
            unsigned gidx = (unsigned)(tb + it * 64 + lane);
            #pragma unroll
            for (int u = 0; u < 8; ++u) {
                // d2 < g  <=>  0.5|c|^2 - q.c < 0.5(g - |q|^2)
                float tt = fmaf(-c.x, sqx[u], hn);
                tt = fmaf(-c.y, sqy[u], tt);
                tt = fmaf(-c.z, sqz[u], tt);
                bool pass = tt < shq[u];
                unsigned long long m = __ballot(pass);
                if (m) {
                    unsigned pre = mbcnt64(m);
                    if (pass) {
                        unsigned slot = min(scnt[u] + pre, (unsigned)(SSTRIDE - 1));
                        surv[(w * 8 + u) * SSTRIDE + slot] = (unsigned short)gidx;
                    }
                    scnt[u] += (unsigned)__popcll(m);  // wave-uniform (SGPR)
                }
            }
            c = cn;
        }
    }
    if (lane == 0) {
        #pragma unroll
        for (int u = 0; u < 8; ++u) cnts[w * 8 + u] = scnt[u];
    }
    __syncthreads();   // B1

    // ---- Phase B: 4 lanes per query ----
    const int qq = lane >> 2;            // query within half 0..15
    const int h = lane & 3;              // sub-lane
    const int myq = (w & 1) * 16 + qq;   // query 0..31
    float4 qv = pbuf4[eighth * NQ + myq];
    const float pqx = qv.x, pqy = qv.y, pqz = qv.z;

    double ngx = 0, ngy = 0, ngz = 0, svg = 0;

    if (w < 2) {
        // Global top-16: split survivors 4 ways, gated bubble, butterfly merge.
        unsigned gl[KNN];
        #pragma unroll
        for (int m = 0; m < KNN; ++m) gl[m] = 0xFFFFFFFFu;
        unsigned cnt = cnts[myq];
        bool valid = (cnt >= KNN) && (cnt <= SSTRIDE);
        if (valid) {
            unsigned share = (cnt + 3) >> 2;
            unsigned m0 = h * share;
            unsigned m1 = min(m0 + share, cnt);
            #pragma unroll 1
            for (unsigned m = m0; m < m1; ++m) {
                unsigned idx = surv[myq * SSTRIDE + m];
                float cx = base[idx * 3 + 0];
                float cy = base[idx * 3 + 1];
                float cz = base[idx * 3 + 2];
                float dx = pqx - cx, dy = pqy - cy, dz = pqz - cz;
                float d2 = dx * dx + dy * dy + dz * dz;   // reference-form d2
                unsigned k = mkkey(d2, idx);
                if (k < gl[KNN - 1]) insert16(k, gl);
            }
        }
        merge4(gl, lane);
        if (valid) {
            // margin check: all filtered-out points provably outside 16th bucket
            float g = gbuf[myq];
            float upper = __uint_as_float((gl[KNN - 1] & 0xFFFFE000u) + 0x2000u);
            valid = (upper < g * 0.999f - 1e-5f);
        }
        if (__any((h == 0 && !valid) ? 1 : 0)) {
            if (h == 0 && !valid) {   // exact fallback (P ~ 1e-9/query)
                #pragma unroll
                for (int m = 0; m < KNN; ++m) gl[m] = 0xFFFFFFFFu;
                #pragma unroll 1
                for (int i = 0; i < NPTS; ++i) {
                    float cx = base[i * 3 + 0];
                    float cy = base[i * 3 + 1];
                    float cz = base[i * 3 + 2];
                    float dx = pqx - cx, dy = pqy - cy, dz = pqz - cz;
                    float d2 = dx * dx + dy * dy + dz * dz;
                    unsigned k = mkkey(d2, (unsigned)i);
                    if (k < gl[KNN - 1]) insert16(k, gl);
                }
            }
        }
        if (h == 0) {
            double c00 = 0, c11 = 0, c22 = 0, c01 = 0, c02 = 0, c12 = 0;
            const double qxd = pqx, qyd = pqy, qzd = pqz;
            #pragma unroll
            for (int m = 0; m < KNN; ++m) {
                int idx = (int)(gl[m] & 0x1FFFu);
                double dx = (double)base[idx * 3 + 0] - qxd;
                double dy = (double)base[idx * 3 + 1] - qyd;
                double dz = (double)base[idx * 3 + 2] - qzd;
                c00 += dx * dx; c11 += dy * dy; c22 += dz * dz;
                c01 += dx * dy; c02 += dx * dz; c12 += dy * dz;
            }
            double lmin, lsum;
            eig3(c00, c11, c22, c01, c02, c12, ngx, ngy, ngz, lmin, lsum);
            svg = lmin / lsum;
        }
    } else {
        // Patch kNN: 4 lanes x 64 patch points, gated bubble, butterfly merge.
        unsigned pl[KNN];
        #pragma unroll
        for (int m = 0; m < KNN; ++m) pl[m] = 0xFFFFFFFFu;
        const int j0 = h * 64;
        #pragma unroll 1
        for (int j = j0; j < j0 + 64; ++j) {
            float4 c = pbuf4[j];
            float dx = pqx - c.x, dy = pqy - c.y, dz = pqz - c.z;
            float d2 = dx * dx + dy * dy + dz * dz;
            unsigned k = mkkey(d2, (unsigned)j);
            if (k < pl[KNN - 1]) insert16(k, pl);
        }
        merge4(pl, lane);
        if (h == 0) {
            double c00 = 0, c11 = 0, c22 = 0, c01 = 0, c02 = 0, c12 = 0;
            const double qxd = pqx, qyd = pqy, qzd = pqz;
            #pragma unroll
            for (int m = 0; m < KNN; ++m) {
                int idx = (int)(pl[m] & 0x1FFFu);
                float4 cpt = pbuf4[idx];
                double dx = (double)cpt.x - qxd;
                double dy = (double)cpt.y - qyd;
                double dz = (double)cpt.z - qzd;
                c00 += dx * dx; c11 += dy * dy; c22 += dz * dz;
                c01 += dx * dy; c02 += dx * dz; c12 += dy * dz;
            }
            double nx, ny, nz, lmin, lsum;
            eig3(c00, c11, c22, c01, c02, c12, nx, ny, nz, lmin, lsum);
            xbuf[myq * 4 + 0] = nx;
            xbuf[myq * 4 + 1] = ny;
            xbuf[myq * 4 + 2] = nz;
            xbuf[myq * 4 + 3] = lmin / lsum;
        }
    }
    __syncthreads();   // B2

    double ln = 0.0, lsv = 0.0;
    if (w < 2 && h == 0) {
        double npx = xbuf[myq * 4 + 0];
        double npy = xbuf[myq * 4 + 1];
        double npz = xbuf[myq * 4 + 2];
        double svp = xbuf[myq * 4 + 3];
        double dx = fabs(npx) - fabs(ngx);
        double dy = fabs(npy) - fabs(ngy);
        double dz = fabs(npz) - fabs(ngz);
        ln  = sqrt(dx * dx + dy * dy + dz * dz);
        double ds = svp - svg;
        lsv = ds * ds;
    }
    if (w < 2) {
        #pragma unroll
        for (int o = 32; o > 0; o >>= 1) {
            ln  += __shfl_down(ln, o);
            lsv += __shfl_down(lsv, o);
        }
        if (lane == 0) { rb[w * 2 + 0] = ln; rb[w * 2 + 1] = lsv; }
    }
    __syncthreads();   // B3
    if (t == 0) {
        const double inv = 1.0 / (double)(NBATCH * NPTS);
        atomicAdd(&out[0], (float)((rb[0] + rb[2]) * inv));
        atomicAdd(&out[1], (float)((rb[1] + rb[3]) * inv));
    }
}

extern "C" void kernel_launch(void* const* d_in, const int* in_sizes, int n_in,
                              void* d_out, int out_size, void* d_ws, size_t ws_size,
                              hipStream_t stream)
{
    const float* pts = (const float*)d_in[0];
    float* out = (float*)d_out;
    hipLaunchKernelGGL(zero2_kernel, dim3(1), dim3(1), 0, stream, out);
    dim3 grid(NPATCH, 8, NBATCH);
    hipLaunchKernelGGL(spl_main, grid, dim3(256), 0, stream, pts, out);
}